// Round 3
// baseline (143.563 us; speedup 1.0000x reference)
//
#include <hip/hip_runtime.h>
#include <math.h>

#define NB 2048

__device__ __forceinline__ float signf_(float x) {
    return (x > 0.0f) ? 1.0f : ((x < 0.0f) ? -1.0f : 0.0f);
}

// Fused kernel: per (s,b) pair computes M = (eq@W + bias) * env in f64, then
// a_sign/a_log via ONE 16x16 f64 LU + transposed solve (cofactor identity:
// det(minor_i0) = (-1)^i det(M) (M^-T e0)_i, so the reference's alt (-1)^i
// cancels), then writes out_sign/out_log for the 16x128 eq tile.
// Block = 256 threads = 4 waves; wave w owns pair P = blockIdx*4 + w.
// NOTE: no MFMA this round — the f64 MFMA fragment layout was the only
// unverified mapping and the round-2 absmax (13.4 ~ a_log spread) matches a
// row-permuted M, i.e. a wrong D-fragment layout. VALU path has the same
// row/col convention as the rest of the kernel by construction.
__global__ __launch_bounds__(256, 3)
void slogcof_kernel(const float* __restrict__ eq,
                    const float* __restrict__ rei,
                    const float* __restrict__ Wm,
                    const float* __restrict__ bias,
                    const float* __restrict__ env_a,
                    const float* __restrict__ env_ion,
                    float* __restrict__ out)
{
    __shared__ float  sEq[4][16][132];   // padded row stride (132*4B = 16B-aligned rows)
    __shared__ double sM[4][16][18];     // 18-double rows
    __shared__ double sDist[4][16][8];
    __shared__ float  sA[4][2][16];      // [pair][sign/log][n]

    const int tid = threadIdx.x;
    const int w   = tid >> 6;           // wave id = pair slot in block
    const int l   = tid & 63;           // lane
    const int P   = blockIdx.x * 4 + w; // global pair id (4096 total)
    const int s   = P >> 11;            // spin
    const int bb  = P & (NB - 1);       // batch

    const int o16 = l & 15;             // orbital column
    const int q4  = l >> 4;             // 4-row group

    // ---- stage eq[16][128] (f32) coalesced into LDS ----
    const float* eqp = eq + (size_t)bb * 4096 + s * 2048;
    #pragma unroll
    for (int it = 0; it < 8; ++it) {
        const int idx = it * 256 + l * 4;
        const float4 v = *reinterpret_cast<const float4*>(eqp + idx);
        *reinterpret_cast<float4*>(&sEq[w][idx >> 7][idx & 127]) = v;
    }

    // ---- distances (f64): 128 values per pair, 2 per lane ----
    #pragma unroll
    for (int rep = 0; rep < 2; ++rep) {
        const int n = (l >> 3) + rep * 8;
        const int i = l & 7;
        const float* rp = rei + (size_t)bb * 768 + s * 384 + n * 24 + i * 3;
        const double x = (double)rp[0], y = (double)rp[1], z = (double)rp[2];
        sDist[w][n][i] = sqrt(x * x + y * y + z * z);
    }

    __syncthreads();

    // ---- linear = eq @ W in f64 (VALU; verified index convention) ----
    // lane (q4,o16) computes rows 4*q4+j (j=0..3), column o16.
    double accv[4] = {0.0, 0.0, 0.0, 0.0};
    {
        const float* Wp = Wm + s * 2048;
        #pragma unroll 4
        for (int d0 = 0; d0 < 128; d0 += 4) {
            const float4 a0 = *reinterpret_cast<const float4*>(&sEq[w][4 * q4 + 0][d0]);
            const float4 a1 = *reinterpret_cast<const float4*>(&sEq[w][4 * q4 + 1][d0]);
            const float4 a2 = *reinterpret_cast<const float4*>(&sEq[w][4 * q4 + 2][d0]);
            const float4 a3 = *reinterpret_cast<const float4*>(&sEq[w][4 * q4 + 3][d0]);
            const double w0 = (double)Wp[(d0 + 0) * 16 + o16];
            const double w1 = (double)Wp[(d0 + 1) * 16 + o16];
            const double w2 = (double)Wp[(d0 + 2) * 16 + o16];
            const double w3 = (double)Wp[(d0 + 3) * 16 + o16];
            accv[0] += (double)a0.x * w0 + (double)a0.y * w1 + (double)a0.z * w2 + (double)a0.w * w3;
            accv[1] += (double)a1.x * w0 + (double)a1.y * w1 + (double)a1.z * w2 + (double)a1.w * w3;
            accv[2] += (double)a2.x * w0 + (double)a2.y * w1 + (double)a2.z * w2 + (double)a2.w * w3;
            accv[3] += (double)a3.x * w0 + (double)a3.y * w1 + (double)a3.z * w2 + (double)a3.w * w3;
        }
    }

    // ---- env (f64) and M ----
    {
        const double bd = (double)bias[s * 16 + o16];
        double ev[4] = {0.0, 0.0, 0.0, 0.0};
        #pragma unroll
        for (int i = 0; i < 8; ++i) {
            const double ea = fabs((double)env_a[s * 128 + i * 16 + o16]);
            const double ei = (double)env_ion[s * 128 + i * 16 + o16];
            #pragma unroll
            for (int j = 0; j < 4; ++j)
                ev[j] += exp(-sDist[w][4 * q4 + j][i] * ea) * ei;
        }
        #pragma unroll
        for (int j = 0; j < 4; ++j)
            sM[w][4 * q4 + j][o16] = (accv[j] + bd) * ev[j];
    }
    __syncthreads();

    // ---- wave 0: LU + transposed solve for the block's 4 pairs ----
    if (w == 0) {
        const int g = q4;     // group = pair slot
        const int j = o16;    // my original row
        double row[16];
        #pragma unroll
        for (int c = 0; c < 16; ++c) row[c] = sM[g][j][c];
        const double m0 = row[0];

        double logdet = 0.0;
        int dsign = 1;
        int used = 0;
        int mystep = -1;

        // row-per-lane LU with partial pivoting (used-flag, no physical swap).
        // key: unused rows carry bit 5 so ANY unused row (even |v|==0) beats
        // every used row; low 4 bits = lane for tie-break.
        #pragma unroll
        for (int k = 0; k < 16; ++k) {
            unsigned key;
            {
                const float av = (float)fabs(row[k]);
                key = used ? (unsigned)j
                           : ((__float_as_uint(av) & 0xFFFFFFC0u) | 0x20u | (unsigned)j);
            }
            #pragma unroll
            for (int off = 8; off >= 1; off >>= 1) {
                const unsigned k2 = (unsigned)__shfl_xor((int)key, off, 16);
                if (k2 > key) key = k2;
            }
            const int p = (int)(key & 15u);
            const double pivv = __shfl(row[k], p, 16);
            logdet += (double)logf((float)fabs(pivv));
            if (pivv < 0.0) dsign = -dsign;
            else if (pivv == 0.0) dsign = 0;
            if (j == p) { used = 1; mystep = k; }
            const double minv = (pivv != 0.0) ? (1.0 / pivv) : 0.0;
            const double mul = row[k] * minv;
            const int upd = !used;
            #pragma unroll
            for (int c = k + 1; c < 16; ++c) {
                const double pv = __shfl(row[c], p, 16);
                if (upd) row[c] -= mul * pv;
            }
            if (upd) row[k] = mul;   // store L multiplier
        }

        // permutation parity via inversions of the mystep sequence
        int invc = 0;
        #pragma unroll
        for (int j2 = 0; j2 < 16; ++j2) {
            const int s2 = __shfl(mystep, j2, 16);
            if (j2 > j && mystep > s2) invc++;
        }
        #pragma unroll
        for (int off = 8; off >= 1; off >>= 1) invc += __shfl_xor(invc, off, 16);
        if (invc & 1) dsign = -dsign;

        // solve U^T wv = e0 (forward over columns o; lane owns w_{mystep})
        double wv = 0.0;
        #pragma unroll
        for (int o = 0; o < 16; ++o) {
            double c0 = (mystep < o) ? (row[o] * wv) : 0.0;
            #pragma unroll
            for (int off = 8; off >= 1; off >>= 1) c0 += __shfl_xor(c0, off, 16);
            if (mystep == o) wv = (((o == 0) ? 1.0 : 0.0) - c0) / row[o];
        }
        // solve L^T vv = wv (backward; unit diagonal); z_j lands lane-local
        double vv = 0.0;
        #pragma unroll
        for (int k = 15; k >= 0; --k) {
            double c0 = (mystep > k) ? (row[k] * vv) : 0.0;
            #pragma unroll
            for (int off = 8; off >= 1; off >>= 1) c0 += __shfl_xor(c0, off, 16);
            if (mystep == k) vv = wv - c0;
        }

        const double zj = vv;
        const float zs = (zj > 0.0) ? 1.0f : ((zj < 0.0) ? -1.0f : 0.0f);
        const float ms = (m0 > 0.0) ? 1.0f : ((m0 < 0.0) ? -1.0f : 0.0f);
        sA[g][0][j] = ms * (float)dsign * zs;
        sA[g][1][j] = logf((float)fabs(m0)) + (float)logdet + logf((float)fabs(zj));
    }
    __syncthreads();

    // ---- output: out[s][0][b][n][d] = sign(eq)*a_sign ; out[s][1][...] = log|eq| + a_log ----
    float* op0 = out + (size_t)s * 8388608 + (size_t)bb * 2048;
    float* op1 = op0 + 4194304;
    #pragma unroll
    for (int it = 0; it < 8; ++it) {
        const int n  = it * 2 + (l >> 5);
        const int d0 = (l & 31) * 4;
        const float4 x = *reinterpret_cast<const float4*>(&sEq[w][n][d0]);
        const float a_s = sA[w][0][n];
        const float a_l = sA[w][1][n];
        float4 osg, olg;
        osg.x = signf_(x.x) * a_s;  olg.x = logf(fabsf(x.x)) + a_l;
        osg.y = signf_(x.y) * a_s;  olg.y = logf(fabsf(x.y)) + a_l;
        osg.z = signf_(x.z) * a_s;  olg.z = logf(fabsf(x.z)) + a_l;
        osg.w = signf_(x.w) * a_s;  olg.w = logf(fabsf(x.w)) + a_l;
        *reinterpret_cast<float4*>(op0 + n * 128 + d0) = osg;
        *reinterpret_cast<float4*>(op1 + n * 128 + d0) = olg;
    }
}

extern "C" void kernel_launch(void* const* d_in, const int* in_sizes, int n_in,
                              void* d_out, int out_size, void* d_ws, size_t ws_size,
                              hipStream_t stream) {
    (void)in_sizes; (void)n_in; (void)out_size; (void)d_ws; (void)ws_size;
    slogcof_kernel<<<dim3(1024), dim3(256), 0, stream>>>(
        (const float*)d_in[0],   // eq_inputs (B,32,128) f32
        (const float*)d_in[1],   // r_ei (B,32,8,3) f32
        (const float*)d_in[2],   // W (2,128,16) f32
        (const float*)d_in[3],   // b (2,16) f32
        (const float*)d_in[4],   // env_a (2,8,16) f32
        (const float*)d_in[5],   // env_ion (2,8,16) f32
        (float*)d_out);          // (2,2,B,16,128) f32
}